// Round 8
// baseline (667.914 us; speedup 1.0000x reference)
//
#include <hip/hip_runtime.h>
#include <hip/hip_bf16.h>
#include <float.h>
#include <math.h>

#define Bz 8
#define Dd 256
#define Tt 2048
#define Kk 8192
#define Mm (Bz*Tt)          // 16384 rows (b*T + t)

// Scorer v8: block = 128 rows x 1024 codes, 512 threads (8 waves: 4wy x 2wx),
// wave-tile 32m x 64n. A register-persistent (full K). B double-buffered LDS,
// staged 128 codes x 64k per step, stride 88 f16 (176 B: uniform bank spread,
// 16B-aligned for b128).
#define NSPL 8
#define BSTR 88

// Rescan chunking
#define CHK 32
#define GRP 16
#define ZG_CAP 4096

// Margin: covers f16 fast-pass score error + np fp32 quantization straddle
#define RESCAN_MARGIN 6e-4f

typedef __attribute__((ext_vector_type(8))) _Float16 f16x8;
typedef __attribute__((ext_vector_type(4))) float    f32x4;

// ---------------------------------------------------------------------------
// numpy-faithful pairwise sum of squares (blocksize-128 pairwise, 8 accums)
// ---------------------------------------------------------------------------
__device__ __forceinline__ float np_sumsq128(const float* __restrict__ x) {
  float r0 = __fmul_rn(x[0], x[0]);
  float r1 = __fmul_rn(x[1], x[1]);
  float r2 = __fmul_rn(x[2], x[2]);
  float r3 = __fmul_rn(x[3], x[3]);
  float r4 = __fmul_rn(x[4], x[4]);
  float r5 = __fmul_rn(x[5], x[5]);
  float r6 = __fmul_rn(x[6], x[6]);
  float r7 = __fmul_rn(x[7], x[7]);
  for (int i = 8; i < 128; i += 8) {
    r0 = __fadd_rn(r0, __fmul_rn(x[i+0], x[i+0]));
    r1 = __fadd_rn(r1, __fmul_rn(x[i+1], x[i+1]));
    r2 = __fadd_rn(r2, __fmul_rn(x[i+2], x[i+2]));
    r3 = __fadd_rn(r3, __fmul_rn(x[i+3], x[i+3]));
    r4 = __fadd_rn(r4, __fmul_rn(x[i+4], x[i+4]));
    r5 = __fadd_rn(r5, __fmul_rn(x[i+5], x[i+5]));
    r6 = __fadd_rn(r6, __fmul_rn(x[i+6], x[i+6]));
    r7 = __fadd_rn(r7, __fmul_rn(x[i+7], x[i+7]));
  }
  return __fadd_rn(__fadd_rn(__fadd_rn(r0, r1), __fadd_rn(r2, r3)),
                   __fadd_rn(__fadd_rn(r4, r5), __fadd_rn(r6, r7)));
}
__device__ __forceinline__ float np_sumsq256(const float* __restrict__ x) {
  return __fadd_rn(np_sumsq128(x), np_sumsq128(x + 128));
}

// ---------------------------------------------------------------------------
// transpose-cast z (B,D,T) f32 -> Ah (M, D) f16
// ---------------------------------------------------------------------------
__global__ void k_cast_z(const float* __restrict__ z, _Float16* __restrict__ Ah) {
  __shared__ _Float16 tile[64][64 + 8];
  const int tid = threadIdx.x;
  const int bidx = blockIdx.x;            // 8 * 4 * 32 = 1024
  const int b  = bidx >> 7;
  const int dt = (bidx >> 5) & 3;
  const int tt = bidx & 31;
  const int d0 = dt * 64, t0 = tt * 64;
  const float* zb = z + ((size_t)b * Dd + d0) * Tt + t0;
  #pragma unroll
  for (int p = 0; p < 4; ++p) {
    const int d  = p * 16 + (tid >> 4);
    const int tl = (tid & 15) * 4;
    const float4 v = *(const float4*)(zb + (size_t)d * Tt + tl);
    tile[tl+0][d] = (_Float16)v.x;
    tile[tl+1][d] = (_Float16)v.y;
    tile[tl+2][d] = (_Float16)v.z;
    tile[tl+3][d] = (_Float16)v.w;
  }
  __syncthreads();
  const int r = tid >> 2, seg = tid & 3;
  const int m = b * Tt + t0 + r;
  int4* dst = (int4*)(Ah + (size_t)m * Dd + d0 + seg * 16);
  const int4* srcv = (const int4*)(&tile[r][seg * 16]);
  dst[0] = srcv[0];
  dst[1] = srcv[1];
}

// ---------------------------------------------------------------------------
// cast codebook f32 -> f16, prescaled by 256 (avoids f16 subnormals)
// ---------------------------------------------------------------------------
__global__ void k_cast_cb(const float* __restrict__ cb, _Float16* __restrict__ Bh) {
  const size_t g = (size_t)blockIdx.x * blockDim.x + threadIdx.x;
  const float4 v0 = *(const float4*)(cb + g * 8);
  const float4 v1 = *(const float4*)(cb + g * 8 + 4);
  f16x8 o;
  o[0] = (_Float16)(v0.x * 256.f); o[1] = (_Float16)(v0.y * 256.f);
  o[2] = (_Float16)(v0.z * 256.f); o[3] = (_Float16)(v0.w * 256.f);
  o[4] = (_Float16)(v1.x * 256.f); o[5] = (_Float16)(v1.y * 256.f);
  o[6] = (_Float16)(v1.z * 256.f); o[7] = (_Float16)(v1.w * 256.f);
  *(f16x8*)(Bh + g * 8) = o;
}

// ---------------------------------------------------------------------------
// np-faithful codebook norms, wave-parallel (8 lanes own np's 8 acc chains)
// ---------------------------------------------------------------------------
__global__ void k_prep(const float* __restrict__ cb, float* __restrict__ sc,
                       double* __restrict__ loss_accum, int* __restrict__ rescan_cnt) {
  const int gid = blockIdx.x * blockDim.x + threadIdx.x;
  if (gid == 0) { *loss_accum = 0.0; *rescan_cnt = 0; }
  const int lane = gid & 63;
  const int j = lane & 7, sub = lane >> 3;
  const int row = (gid >> 6) * 8 + sub;
  if (row >= Kk) return;
  const float* x = cb + (size_t)row * Dd;
  float c0 = __fmul_rn(x[j], x[j]);
  float c1 = __fmul_rn(x[128 + j], x[128 + j]);
  #pragma unroll
  for (int i = 8; i < 128; i += 8) {
    c0 = __fadd_rn(c0, __fmul_rn(x[j + i], x[j + i]));
    c1 = __fadd_rn(c1, __fmul_rn(x[128 + j + i], x[128 + j + i]));
  }
  #pragma unroll
  for (int off = 1; off <= 4; off <<= 1) {
    c0 = __fadd_rn(c0, __shfl_xor(c0, off));
    c1 = __fadd_rn(c1, __shfl_xor(c1, off));
  }
  if (j == 0) sc[row] = __fadd_rn(c0, c1);
}

// ---------------------------------------------------------------------------
// f16 MFMA score pass v8
// ---------------------------------------------------------------------------
#define LOADRB(NT, KC) do {                                                   \
    const _Float16* _p = gBs + (size_t)(NT) * 128 * Dd + (KC) * 64;           \
    rb[0] = *(const int4*)_p; rb[1] = *(const int4*)(_p + 8);                 \
  } while (0)

#define STEP(KC, PRELOAD) do {                                                \
    __syncthreads();                       /* reads of Bs[buf] (s-2) done */  \
    {                                                                         \
      _Float16* _wp = &Bs[(KC) & 1][0] + srow * BSTR + sseg * 16;             \
      *(int4*)_wp = rb[0]; *(int4*)(_wp + 8) = rb[1];                         \
    }                                                                         \
    __syncthreads();                                                          \
    PRELOAD;                                                                  \
    f16x8 bfr[4][2];                                                          \
    _Pragma("unroll")                                                         \
    for (int ni = 0; ni < 4; ++ni)                                            \
      _Pragma("unroll")                                                       \
      for (int ks = 0; ks < 2; ++ks)                                          \
        bfr[ni][ks] = *(const f16x8*)(&Bs[(KC) & 1][0] +                      \
            (wx * 64 + ni * 16 + l15) * BSTR + ks * 32 + quad * 8);           \
    _Pragma("unroll")                                                         \
    for (int ks = 0; ks < 2; ++ks)                                            \
      _Pragma("unroll")                                                       \
      for (int mi = 0; mi < 2; ++mi)                                          \
        _Pragma("unroll")                                                     \
        for (int ni = 0; ni < 4; ++ni)                                        \
          acc[mi][ni] = __builtin_amdgcn_mfma_f32_16x16x32_f16(               \
              af[KC][ks][mi], bfr[ni][ks], acc[mi][ni], 0, 0, 0);             \
  } while (0)

__global__ __launch_bounds__(512, 1)
void k_mfma(const _Float16* __restrict__ Ah, const _Float16* __restrict__ Bh,
            const float* __restrict__ sc,
            float* __restrict__ pd1, float* __restrict__ pd2, int* __restrict__ pi1) {
  __shared__ __align__(16) _Float16 Bs[2][128 * BSTR];   // 45,056 B
  __shared__ float red1[128 * 2];
  __shared__ float red2[128 * 2];
  __shared__ int   redi[128 * 2];

  const int tid = threadIdx.x;
  const int bx  = blockIdx.x & 7;        // n-split; XCD = blockIdx%8 -> B-slab/XCD
  const int by  = blockIdx.x >> 3;       // 0..127
  const int m0  = by * 128, n0 = bx * 1024;
  const int w   = tid >> 6, lane = tid & 63;
  const int wy  = w >> 1, wx = w & 1;
  const int l15 = lane & 15, quad = lane >> 4;

  // ---- A: 64 VGPRs/wave, persistent, statically indexed everywhere
  f16x8 af[4][2][2];
  {
    const _Float16* gA = Ah + (size_t)(m0 + wy * 32 + l15) * Dd + quad * 8;
    #pragma unroll
    for (int kc = 0; kc < 4; ++kc)
      #pragma unroll
      for (int ks = 0; ks < 2; ++ks)
        #pragma unroll
        for (int mi = 0; mi < 2; ++mi)
          af[kc][ks][mi] = *(const f16x8*)(gA + (size_t)mi * 16 * Dd + kc * 64 + ks * 32);
  }

  // ---- B staging role: 4 threads/code, 32 B each
  const int srow = tid >> 2, sseg = tid & 3;
  const _Float16* gBs = Bh + (size_t)(n0 + srow) * Dd + sseg * 16;

  int4 rb[2];
  f32x4 acc[2][4];
  #pragma unroll
  for (int mi = 0; mi < 2; ++mi)
    #pragma unroll
    for (int ni = 0; ni < 4; ++ni)
      acc[mi][ni] = (f32x4){0.f, 0.f, 0.f, 0.f};

  float s1[8], s2[8]; int i1[8];
  #pragma unroll
  for (int q = 0; q < 8; ++q) { s1[q] = INFINITY; s2[q] = INFINITY; i1[q] = 0x7fffffff; }

  LOADRB(0, 0);

  for (int nt = 0; nt < 8; ++nt) {
    float scv[4];
    #pragma unroll
    for (int ni = 0; ni < 4; ++ni)
      scv[ni] = sc[n0 + nt * 128 + wx * 64 + ni * 16 + l15];

    STEP(0, LOADRB(nt, 1));
    STEP(1, LOADRB(nt, 2));
    STEP(2, LOADRB(nt, 3));
    STEP(3, LOADRB((nt + 1) & 7, 0));    // wrap load on last nt: harmless

    // fold this 128-col n-tile into per-thread top-2 (k ascending)
    #pragma unroll
    for (int mi = 0; mi < 2; ++mi)
      #pragma unroll
      for (int r = 0; r < 4; ++r) {
        const int q = mi * 4 + r;
        #pragma unroll
        for (int ni = 0; ni < 4; ++ni) {
          const float sv = fmaf(-0.0078125f, acc[mi][ni][r], scv[ni]);  // -2/256
          const int   k  = n0 + nt * 128 + wx * 64 + ni * 16 + l15;
          if (sv < s1[q]) { s2[q] = s1[q]; s1[q] = sv; i1[q] = k; }
          else if (sv < s2[q]) s2[q] = sv;
          acc[mi][ni][r] = 0.f;
        }
      }
  }

  // ---- merge across the 16 lanes of each quad (same rows, different cols)
  #pragma unroll
  for (int off = 1; off <= 8; off <<= 1)
    #pragma unroll
    for (int q = 0; q < 8; ++q) {
      const float o1 = __shfl_xor(s1[q], off);
      const float o2 = __shfl_xor(s2[q], off);
      const int   oi = __shfl_xor(i1[q], off);
      if (o1 < s1[q] || (o1 == s1[q] && oi < i1[q])) {
        s2[q] = fminf(s1[q], o2); s1[q] = o1; i1[q] = oi;
      } else s2[q] = fminf(s2[q], o1);
    }

  // ---- cross-wave (wx) merge through LDS
  __syncthreads();
  if (l15 == 0) {
    #pragma unroll
    for (int mi = 0; mi < 2; ++mi)
      #pragma unroll
      for (int r = 0; r < 4; ++r) {
        const int q  = mi * 4 + r;
        const int ml = wy * 32 + mi * 16 + quad * 4 + r;   // 0..127
        red1[ml * 2 + wx] = s1[q];
        red2[ml * 2 + wx] = s2[q];
        redi[ml * 2 + wx] = i1[q];
      }
  }
  __syncthreads();
  if (tid < 128) {
    float a1 = red1[tid * 2], a2 = red2[tid * 2]; int ai = redi[tid * 2];
    const float b1 = red1[tid * 2 + 1], b2 = red2[tid * 2 + 1];
    const int   bi = redi[tid * 2 + 1];
    if (b1 < a1 || (b1 == a1 && bi < ai)) { a2 = fminf(a1, b2); a1 = b1; ai = bi; }
    else a2 = fminf(a2, b1);
    const size_t o = (size_t)bx * Mm + (size_t)(m0 + tid);
    pd1[o] = a1; pd2[o] = a2; pi1[o] = ai;
  }
}

// ---------------------------------------------------------------------------
// combine the NSPL partials per row; flag near-ties for np rescan
// ---------------------------------------------------------------------------
__global__ void k_combine(const float* __restrict__ pd1, const float* __restrict__ pd2,
                          const int* __restrict__ pi1, int* __restrict__ idxf,
                          int* __restrict__ rescan_cnt, int* __restrict__ rlist,
                          float* __restrict__ outIdx) {
  const int m = blockIdx.x * blockDim.x + threadIdx.x;
  if (m >= Mm) return;
  float a1 = INFINITY, a2 = INFINITY; int ai = 0x7fffffff;
  #pragma unroll
  for (int spl = 0; spl < NSPL; ++spl) {       // spl ascending -> k ascending
    const size_t o = (size_t)spl * Mm + m;
    const float b1 = pd1[o], b2 = pd2[o]; const int bi = pi1[o];
    if (b1 < a1 || (b1 == a1 && bi < ai)) { a2 = fminf(a1, b2); a1 = b1; ai = bi; }
    else a2 = fminf(a2, b1);
  }
  idxf[m]   = ai;
  outIdx[m] = (float)ai;
  if (a2 - a1 <= RESCAN_MARGIN) { const int p = atomicAdd(rescan_cnt, 1); rlist[p] = m; }
}

// ---------------------------------------------------------------------------
// gather flagged rows into compact zg; np norms; init packed minima
// ---------------------------------------------------------------------------
__global__ void k_gather(const float* __restrict__ z, const int* __restrict__ rescan_cnt,
                         const int* __restrict__ rlist, float* __restrict__ zg,
                         float* __restrict__ Ag, unsigned long long* __restrict__ pbrow) {
  __shared__ float zr[Dd];
  const int cnt = min(*rescan_cnt, ZG_CAP);
  for (int it = blockIdx.x; it < cnt; it += gridDim.x) {
    const int m = rlist[it];
    const int b = m / Tt, t = m & (Tt - 1);
    __syncthreads();
    zr[threadIdx.x] = z[(size_t)b * Dd * Tt + (size_t)threadIdx.x * Tt + t];
    __syncthreads();
    zg[(size_t)it * Dd + threadIdx.x] = zr[threadIdx.x];
    if (threadIdx.x == 0) { Ag[it] = np_sumsq256(zr); pbrow[it] = ~0ull; }
  }
}

// ---------------------------------------------------------------------------
// chunked np-faithful rescan: packed (orderable f32, idx) atomicMin per row
// ---------------------------------------------------------------------------
__global__ __launch_bounds__(256)
void k_rescan_part(const float* __restrict__ cb, const float* __restrict__ sc,
                   const int* __restrict__ rescan_cnt, const float* __restrict__ zg,
                   const float* __restrict__ Ag, unsigned long long* __restrict__ pbrow) {
  __shared__ float  cs[CHK * 257];
  __shared__ float  scs[CHK];
  __shared__ float  zf[Dd];
  __shared__ double pr[256];
  const int tid = threadIdx.x;
  const int cnt = min(*rescan_cnt, ZG_CAP);
  const int c = blockIdx.x >> 4;
  const int g = blockIdx.x & (GRP - 1);
  if (g >= cnt) return;
  const int k0 = c * CHK;
  for (int i = tid; i < CHK * Dd; i += 256) {
    const int code = i >> 8, d = i & 255;
    cs[code * 257 + d] = cb[(size_t)(k0 + code) * Dd + d];
  }
  if (tid < CHK) scs[tid] = sc[k0 + tid];
  const int code = tid & 31, seg = tid >> 5;
  __syncthreads();
  for (int it = g; it < cnt; it += GRP) {
    zf[tid] = zg[(size_t)it * Dd + tid];
    __syncthreads();
    const float* cp = &cs[code * 257 + seg * 32];
    const float* zp = &zf[seg * 32];
    double a0 = 0.0, a1 = 0.0, a2 = 0.0, a3 = 0.0;
    #pragma unroll
    for (int j = 0; j < 32; j += 4) {
      a0 = fma((double)cp[j+0], (double)zp[j+0], a0);
      a1 = fma((double)cp[j+1], (double)zp[j+1], a1);
      a2 = fma((double)cp[j+2], (double)zp[j+2], a2);
      a3 = fma((double)cp[j+3], (double)zp[j+3], a3);
    }
    pr[tid] = (a0 + a1) + (a2 + a3);
    __syncthreads();
    if (tid < CHK) {
      double M8 = 0.0;
      #pragma unroll
      for (int sg = 0; sg < 8; ++sg) M8 += pr[tid + sg * 32];
      const float M  = (float)M8;
      const float t1 = __fsub_rn(Ag[it], __fmul_rn(2.0f, M));
      const float dq = __fadd_rn(t1, scs[tid]);
      unsigned int fb = __float_as_uint(dq);
      fb = (fb & 0x80000000u) ? ~fb : (fb | 0x80000000u);
      unsigned long long pack = ((unsigned long long)fb << 32) | (unsigned)(k0 + tid);
      #pragma unroll
      for (int off = 16; off; off >>= 1) {
        const unsigned long long o = __shfl_xor(pack, off);
        if (o < pack) pack = o;
      }
      if (tid == 0) atomicMin(pbrow + it, pack);
    }
    __syncthreads();
  }
}

__global__ void k_rescan_final(const int* __restrict__ rescan_cnt, const int* __restrict__ rlist,
                               const unsigned long long* __restrict__ pbrow,
                               int* __restrict__ idxf, float* __restrict__ outIdx) {
  const int cnt = min(*rescan_cnt, ZG_CAP);
  const int it = blockIdx.x * blockDim.x + threadIdx.x;
  if (it < cnt) {
    const int idx = (int)(unsigned)(pbrow[it] & 0xFFFFFFFFull);
    const int m = rlist[it];
    idxf[m] = idx; outIdx[m] = (float)idx;
  }
}

// overflow fallback: normally 0 iterations
__global__ void k_rescan_slow(const float* __restrict__ z, const float* __restrict__ cb,
                              const float* __restrict__ sc,
                              const int* __restrict__ rescan_cnt, const int* __restrict__ rlist,
                              int* __restrict__ idxf, float* __restrict__ outIdx) {
  __shared__ float zrow[Dd];
  __shared__ float Ash;
  __shared__ float sval[256];
  __shared__ int   sidx[256];
  const int tid = threadIdx.x;
  const int cnt = *rescan_cnt;
  for (int it = ZG_CAP + blockIdx.x; it < cnt; it += gridDim.x) {
    const int m = rlist[it];
    const int b = m / Tt, t = m & (Tt - 1);
    __syncthreads();
    zrow[tid] = z[(size_t)b * Dd * Tt + (size_t)tid * Tt + t];
    __syncthreads();
    if (tid == 0) Ash = np_sumsq256(zrow);
    __syncthreads();
    const float A = Ash;
    float best = INFINITY; int bi = 0x7fffffff;
    for (int k = tid; k < Kk; k += 256) {
      const float* cr = cb + (size_t)k * Dd;
      double a0 = 0.0, a1 = 0.0, a2 = 0.0, a3 = 0.0;
      for (int d = 0; d < Dd; d += 4) {
        const float4 c4 = *(const float4*)(cr + d);
        a0 = fma((double)c4.x, (double)zrow[d+0], a0);
        a1 = fma((double)c4.y, (double)zrow[d+1], a1);
        a2 = fma((double)c4.z, (double)zrow[d+2], a2);
        a3 = fma((double)c4.w, (double)zrow[d+3], a3);
      }
      const float M  = (float)((a0 + a1) + (a2 + a3));
      const float t1 = __fsub_rn(A, __fmul_rn(2.0f, M));
      const float dq = __fadd_rn(t1, sc[k]);
      if (dq < best) { best = dq; bi = k; }
    }
    sval[tid] = best; sidx[tid] = bi;
    __syncthreads();
    for (int off = 128; off; off >>= 1) {
      if (tid < off) {
        if (sval[tid+off] < sval[tid] ||
            (sval[tid+off] == sval[tid] && sidx[tid+off] < sidx[tid])) {
          sval[tid] = sval[tid+off]; sidx[tid] = sidx[tid+off];
        }
      }
      __syncthreads();
    }
    if (tid == 0) { idxf[m] = sidx[0]; outIdx[m] = (float)sidx[0]; }
    __syncthreads();
  }
}

// ---------------------------------------------------------------------------
// fused gather + transpose + STE + loss: out[b][d][t] = z + (cb[idx] - z)
// ---------------------------------------------------------------------------
__global__ void k_out(const float* __restrict__ z, const float* __restrict__ cb,
                      const int* __restrict__ idxf,
                      float* __restrict__ outZ, double* __restrict__ loss_accum) {
  __shared__ float tile[64][65];          // [d][t]
  const int tid = threadIdx.x;
  const int bidx = blockIdx.x;            // 8 * 4 * 32 = 1024
  const int b  = bidx >> 7;
  const int dt = (bidx >> 5) & 3;
  const int tt = bidx & 31;
  const int d0 = dt * 64, t0 = tt * 64;
  // phase 1: gather cb rows coalesced (4 threads per row)
  {
    const int r = tid >> 2, seg = tid & 3;
    const int idx = idxf[b * Tt + t0 + r];
    const float* src = cb + (size_t)idx * Dd + d0 + seg * 16;
    #pragma unroll
    for (int q4 = 0; q4 < 4; ++q4) {
      const float4 v = *(const float4*)(src + q4 * 4);
      tile[seg * 16 + q4 * 4 + 0][r] = v.x;
      tile[seg * 16 + q4 * 4 + 1][r] = v.y;
      tile[seg * 16 + q4 * 4 + 2][r] = v.z;
      tile[seg * 16 + q4 * 4 + 3][r] = v.w;
    }
  }
  __syncthreads();
  // phase 2: write out along t, fuse STE + loss
  const float* zbase = z + ((size_t)b * Dd + d0) * Tt + t0;
  float*       obase = outZ + ((size_t)b * Dd + d0) * Tt + t0;
  double ls = 0.0;
  #pragma unroll
  for (int p = 0; p < 4; ++p) {
    const int d  = p * 16 + (tid >> 4);
    const int t4 = (tid & 15) * 4;
    const float4 zv = *(const float4*)(zbase + (size_t)d * Tt + t4);
    const float q0 = tile[d][t4+0], q1 = tile[d][t4+1];
    const float q2 = tile[d][t4+2], q3 = tile[d][t4+3];
    const float r0 = q0 - zv.x, r1 = q1 - zv.y, r2 = q2 - zv.z, r3 = q3 - zv.w;
    float4 o;
    o.x = zv.x + r0; o.y = zv.y + r1; o.z = zv.z + r2; o.w = zv.w + r3;
    *(float4*)(obase + (size_t)d * Tt + t4) = o;
    ls += (double)r0*r0 + (double)r1*r1 + (double)r2*r2 + (double)r3*r3;
  }
  #pragma unroll
  for (int off = 32; off; off >>= 1) ls += __shfl_down(ls, off);
  if ((tid & 63) == 0) atomicAdd(loss_accum, ls);
}

__global__ void k_finalize(const double* __restrict__ loss_accum, float* __restrict__ outLoss) {
  const double mean = *loss_accum / (double)((size_t)Bz * Dd * Tt);
  *outLoss = (float)(mean + 0.1 * mean);
}

// ---------------------------------------------------------------------------
extern "C" void kernel_launch(void* const* d_in, const int* in_sizes, int n_in,
                              void* d_out, int out_size, void* d_ws, size_t ws_size,
                              hipStream_t stream) {
  (void)in_sizes; (void)n_in; (void)out_size; (void)ws_size;
  const float* z  = (const float*)d_in[0];   // (B, D, T) fp32
  const float* cb = (const float*)d_in[1];   // (K, D)    fp32

  float* outZ    = (float*)d_out;
  float* outIdx  = outZ + (size_t)Bz * Dd * Tt;
  float* outLoss = outIdx + Mm;

  char* w = (char*)d_ws;
  double*    loss_accum = (double*)w;    w += 16;
  int*       rescan_cnt = (int*)w;       w += 16;
  int*       rlist      = (int*)w;       w += sizeof(int)   * Mm;
  int*       idxf       = (int*)w;       w += sizeof(int)   * Mm;
  float*     sc         = (float*)w;     w += sizeof(float) * Kk;
  _Float16*  Ah         = (_Float16*)w;  w += sizeof(_Float16) * (size_t)Mm * Dd;
  _Float16*  Bh         = (_Float16*)w;  w += sizeof(_Float16) * (size_t)Kk * Dd;
  float*     zg         = (float*)w;     w += sizeof(float) * (size_t)ZG_CAP * Dd;
  float*     Ag         = (float*)w;     w += sizeof(float) * ZG_CAP;
  unsigned long long* pbrow = (unsigned long long*)w; w += sizeof(unsigned long long) * ZG_CAP;
  float*     pd1        = (float*)w;     w += sizeof(float) * (size_t)NSPL * Mm;
  float*     pd2        = (float*)w;     w += sizeof(float) * (size_t)NSPL * Mm;
  int*       pi1        = (int*)w;       /* total ~24 MB */

  k_cast_z      <<<dim3(1024), 256, 0, stream>>>(z, Ah);
  k_cast_cb     <<<dim3((Kk * Dd / 8) / 256), 256, 0, stream>>>(cb, Bh);
  k_prep        <<<dim3(Kk * 8 / 256), 256, 0, stream>>>(cb, sc, loss_accum, rescan_cnt);
  k_mfma        <<<dim3((Mm / 128) * NSPL), 512, 0, stream>>>(Ah, Bh, sc, pd1, pd2, pi1);
  k_combine     <<<dim3(Mm / 256), 256, 0, stream>>>(pd1, pd2, pi1, idxf, rescan_cnt, rlist, outIdx);
  k_gather      <<<dim3(256), 256, 0, stream>>>(z, rescan_cnt, rlist, zg, Ag, pbrow);
  k_rescan_part <<<dim3((Kk / CHK) * GRP), 256, 0, stream>>>(cb, sc, rescan_cnt, zg, Ag, pbrow);
  k_rescan_slow <<<dim3(64), 256, 0, stream>>>(z, cb, sc, rescan_cnt, rlist, idxf, outIdx);
  k_rescan_final<<<dim3(ZG_CAP / 256), 256, 0, stream>>>(rescan_cnt, rlist, pbrow, idxf, outIdx);
  k_out         <<<dim3(1024), 256, 0, stream>>>(z, cb, idxf, outZ, loss_accum);
  k_finalize    <<<dim3(1), 1, 0, stream>>>(loss_accum, outLoss);
}

// Round 9
// 569.779 us; speedup vs baseline: 1.1722x; 1.1722x over previous
//
#include <hip/hip_runtime.h>
#include <hip/hip_bf16.h>
#include <float.h>
#include <math.h>

#define Bz 8
#define Dd 256
#define Tt 2048
#define Kk 8192
#define Mm (Bz*Tt)          // 16384 rows (b*T + t)

// Scorer v9 (m97 template): block = 128 rows x 256 cols, 256 thr (4 waves,
// 64x64 wave-tiles), K-loop = nt(2) x kc(4); A+B tiles staged per step via
// global_load_lds (async DMA, no VGPR round-trip), dense 128B rows with XOR
// bank swizzle. Top-2 fold per nt -> 64 column splits.
#define NSPL 64

// Rescan chunking
#define CHK 32
#define GRP 16
#define ZG_CAP 4096

// Margin: covers f16 fast-pass score error + np fp32 quantization straddle
#define RESCAN_MARGIN 6e-4f

typedef __attribute__((ext_vector_type(8))) _Float16 f16x8;
typedef __attribute__((ext_vector_type(4))) float    f32x4;

// async global->LDS DMA, 16 B per lane; lds dest = wave-uniform base + lane*16
__device__ __forceinline__ void gld16(const void* g, void* l) {
  __builtin_amdgcn_global_load_lds(
      (const __attribute__((address_space(1))) void*)g,
      (__attribute__((address_space(3))) void*)l, 16, 0, 0);
}

// ---------------------------------------------------------------------------
// numpy-faithful pairwise sum of squares (blocksize-128 pairwise, 8 accums)
// ---------------------------------------------------------------------------
__device__ __forceinline__ float np_sumsq128(const float* __restrict__ x) {
  float r0 = __fmul_rn(x[0], x[0]);
  float r1 = __fmul_rn(x[1], x[1]);
  float r2 = __fmul_rn(x[2], x[2]);
  float r3 = __fmul_rn(x[3], x[3]);
  float r4 = __fmul_rn(x[4], x[4]);
  float r5 = __fmul_rn(x[5], x[5]);
  float r6 = __fmul_rn(x[6], x[6]);
  float r7 = __fmul_rn(x[7], x[7]);
  for (int i = 8; i < 128; i += 8) {
    r0 = __fadd_rn(r0, __fmul_rn(x[i+0], x[i+0]));
    r1 = __fadd_rn(r1, __fmul_rn(x[i+1], x[i+1]));
    r2 = __fadd_rn(r2, __fmul_rn(x[i+2], x[i+2]));
    r3 = __fadd_rn(r3, __fmul_rn(x[i+3], x[i+3]));
    r4 = __fadd_rn(r4, __fmul_rn(x[i+4], x[i+4]));
    r5 = __fadd_rn(r5, __fmul_rn(x[i+5], x[i+5]));
    r6 = __fadd_rn(r6, __fmul_rn(x[i+6], x[i+6]));
    r7 = __fadd_rn(r7, __fmul_rn(x[i+7], x[i+7]));
  }
  return __fadd_rn(__fadd_rn(__fadd_rn(r0, r1), __fadd_rn(r2, r3)),
                   __fadd_rn(__fadd_rn(r4, r5), __fadd_rn(r6, r7)));
}
__device__ __forceinline__ float np_sumsq256(const float* __restrict__ x) {
  return __fadd_rn(np_sumsq128(x), np_sumsq128(x + 128));
}

// ---------------------------------------------------------------------------
// k_pre: fused [cast_z | cast_cb | prep] by blockIdx range (fewer launches)
// ---------------------------------------------------------------------------
__global__ void k_pre(const float* __restrict__ z, const float* __restrict__ cb,
                      _Float16* __restrict__ Ah, _Float16* __restrict__ Bh,
                      float* __restrict__ sc,
                      double* __restrict__ loss_accum, int* __restrict__ rescan_cnt) {
  const int bid = blockIdx.x;
  const int tid = threadIdx.x;
  if (bid < 1024) {
    // ---- transpose-cast z (B,D,T) f32 -> Ah (M,D) f16
    __shared__ _Float16 tile[64][64 + 8];
    const int b  = bid >> 7;
    const int dt = (bid >> 5) & 3;
    const int tt = bid & 31;
    const int d0 = dt * 64, t0 = tt * 64;
    const float* zb = z + ((size_t)b * Dd + d0) * Tt + t0;
    #pragma unroll
    for (int p = 0; p < 4; ++p) {
      const int d  = p * 16 + (tid >> 4);
      const int tl = (tid & 15) * 4;
      const float4 v = *(const float4*)(zb + (size_t)d * Tt + tl);
      tile[tl+0][d] = (_Float16)v.x;
      tile[tl+1][d] = (_Float16)v.y;
      tile[tl+2][d] = (_Float16)v.z;
      tile[tl+3][d] = (_Float16)v.w;
    }
    __syncthreads();
    const int r = tid >> 2, seg = tid & 3;
    const int m = b * Tt + t0 + r;
    int4* dst = (int4*)(Ah + (size_t)m * Dd + d0 + seg * 16);
    const int4* srcv = (const int4*)(&tile[r][seg * 16]);
    dst[0] = srcv[0];
    dst[1] = srcv[1];
  } else if (bid < 2048) {
    // ---- cast codebook f32 -> f16, prescaled by 256
    const size_t g = (size_t)(bid - 1024) * 256 + tid;
    const float4 v0 = *(const float4*)(cb + g * 8);
    const float4 v1 = *(const float4*)(cb + g * 8 + 4);
    f16x8 o;
    o[0] = (_Float16)(v0.x * 256.f); o[1] = (_Float16)(v0.y * 256.f);
    o[2] = (_Float16)(v0.z * 256.f); o[3] = (_Float16)(v0.w * 256.f);
    o[4] = (_Float16)(v1.x * 256.f); o[5] = (_Float16)(v1.y * 256.f);
    o[6] = (_Float16)(v1.z * 256.f); o[7] = (_Float16)(v1.w * 256.f);
    *(f16x8*)(Bh + g * 8) = o;
  } else {
    // ---- np-faithful codebook norms (8 lanes own np's 8 acc chains)
    if (bid == 2048 && tid == 0) { *loss_accum = 0.0; *rescan_cnt = 0; }
    const int gid = (bid - 2048) * 256 + tid;
    const int lane = gid & 63;
    const int j = lane & 7, sub = lane >> 3;
    const int row = (gid >> 6) * 8 + sub;
    if (row >= Kk) return;
    const float* x = cb + (size_t)row * Dd;
    float c0 = __fmul_rn(x[j], x[j]);
    float c1 = __fmul_rn(x[128 + j], x[128 + j]);
    #pragma unroll
    for (int i = 8; i < 128; i += 8) {
      c0 = __fadd_rn(c0, __fmul_rn(x[j + i], x[j + i]));
      c1 = __fadd_rn(c1, __fmul_rn(x[128 + j + i], x[128 + j + i]));
    }
    #pragma unroll
    for (int off = 1; off <= 4; off <<= 1) {
      c0 = __fadd_rn(c0, __shfl_xor(c0, off));
      c1 = __fadd_rn(c1, __shfl_xor(c1, off));
    }
    if (j == 0) sc[row] = __fadd_rn(c0, c1);
  }
}

// ---------------------------------------------------------------------------
// f16 MFMA score pass v9 (m97 template + XOR swizzle)
// ---------------------------------------------------------------------------
__global__ __launch_bounds__(256, 3)
void k_mfma(const _Float16* __restrict__ Ah, const _Float16* __restrict__ Bh,
            const float* __restrict__ sc,
            float* __restrict__ pd1, float* __restrict__ pd2, int* __restrict__ pi1) {
  __shared__ __align__(16) _Float16 As[128 * 64];   // 16 KB, dense 128 B rows
  __shared__ __align__(16) _Float16 Bs[128 * 64];   // 16 KB
  __shared__ float mr1[256];
  __shared__ float mr2[256];
  __shared__ int   mri[256];

  const int tid  = threadIdx.x;
  const int bx   = blockIdx.x & 31;      // 32 n-tiles of 256 cols
  const int by   = blockIdx.x >> 5;      // 128 m-tiles
  const int m0   = by * 128, n0 = bx * 256;
  const int w    = tid >> 6, lane = tid & 63;
  const int wy   = w >> 1, wx = w & 1;
  const int l15  = lane & 15, quad = lane >> 4;
  const int lhi  = lane >> 3, llo = lane & 7;   // staging roles
  const int sw   = l15 & 7;                     // read-side swizzle key

  f32x4 acc[4][4];
  #pragma unroll
  for (int mi = 0; mi < 4; ++mi)
    #pragma unroll
    for (int ni = 0; ni < 4; ++ni)
      acc[mi][ni] = (f32x4){0.f, 0.f, 0.f, 0.f};

  for (int nt = 0; nt < 2; ++nt) {
    // ---- K loop: stage A(kc) and B(nt,kc) via async DMA, then MFMA
    #pragma unroll
    for (int kc = 0; kc < 4; ++kc) {
      __syncthreads();                           // prior LDS reads done
      #pragma unroll
      for (int c4 = 0; c4 < 4; ++c4) {
        const int c  = w * 4 + c4;               // chunk: 8 rows x 128 B
        const int r8 = c * 8 + lhi;
        const int p  = llo ^ lhi;                // swizzled source chunk
        gld16(Ah + (size_t)(m0 + r8) * Dd + kc * 64 + p * 8, As + c * 512);
        gld16(Bh + (size_t)(n0 + nt * 128 + r8) * Dd + kc * 64 + p * 8, Bs + c * 512);
      }
      __syncthreads();                           // drains vmcnt -> data visible
      #pragma unroll
      for (int ks = 0; ks < 2; ++ks) {
        f16x8 af[4], bf[4];
        #pragma unroll
        for (int mi = 0; mi < 4; ++mi)
          af[mi] = *(const f16x8*)(As + (wy*64 + mi*16 + l15) * 64 + (((ks*4 + quad) ^ sw) * 8));
        #pragma unroll
        for (int ni = 0; ni < 4; ++ni)
          bf[ni] = *(const f16x8*)(Bs + (wx*64 + ni*16 + l15) * 64 + (((ks*4 + quad) ^ sw) * 8));
        #pragma unroll
        for (int mi = 0; mi < 4; ++mi)
          #pragma unroll
          for (int ni = 0; ni < 4; ++ni)
            acc[mi][ni] = __builtin_amdgcn_mfma_f32_16x16x32_f16(af[mi], bf[ni], acc[mi][ni], 0, 0, 0);
      }
    }

    // ---- epilogue for this nt: per-row top-2 over 128 cols
    float scv[4];
    #pragma unroll
    for (int ni = 0; ni < 4; ++ni)
      scv[ni] = sc[n0 + nt * 128 + wx * 64 + ni * 16 + l15];

    float s1[16], s2[16]; int i1[16];
    #pragma unroll
    for (int mi = 0; mi < 4; ++mi)
      #pragma unroll
      for (int r = 0; r < 4; ++r) {
        const int q = mi * 4 + r;
        float a1 = INFINITY, a2 = INFINITY; int ai = 0x7fffffff;
        #pragma unroll
        for (int ni = 0; ni < 4; ++ni) {         // ni ascending -> k ascending
          const float sv = fmaf(-0.0078125f, acc[mi][ni][r], scv[ni]);  // -2/256
          const int   k  = n0 + nt * 128 + wx * 64 + ni * 16 + l15;
          if (sv < a1) { a2 = a1; a1 = sv; ai = k; }
          else if (sv < a2) a2 = sv;
          acc[mi][ni][r] = 0.f;                  // reset for next nt
        }
        s1[q] = a1; s2[q] = a2; i1[q] = ai;
      }

    #pragma unroll
    for (int off = 1; off <= 8; off <<= 1)
      #pragma unroll
      for (int q = 0; q < 16; ++q) {
        const float o1 = __shfl_xor(s1[q], off);
        const float o2 = __shfl_xor(s2[q], off);
        const int   oi = __shfl_xor(i1[q], off);
        if (o1 < s1[q] || (o1 == s1[q] && oi < i1[q])) {
          s2[q] = fminf(s1[q], o2); s1[q] = o1; i1[q] = oi;
        } else s2[q] = fminf(s2[q], o1);
      }

    __syncthreads();                             // As/Bs reads done; mr reuse ok
    if (l15 == 0) {
      #pragma unroll
      for (int mi = 0; mi < 4; ++mi)
        #pragma unroll
        for (int r = 0; r < 4; ++r) {
          const int q  = mi * 4 + r;
          const int ml = wy * 64 + mi * 16 + quad * 4 + r;   // 0..127
          mr1[ml * 2 + wx] = s1[q];
          mr2[ml * 2 + wx] = s2[q];
          mri[ml * 2 + wx] = i1[q];
        }
    }
    __syncthreads();
    if (tid < 128) {
      float a1 = mr1[tid * 2], a2 = mr2[tid * 2]; int ai = mri[tid * 2];
      const float b1 = mr1[tid * 2 + 1], b2 = mr2[tid * 2 + 1];
      const int   bi = mri[tid * 2 + 1];
      if (b1 < a1 || (b1 == a1 && bi < ai)) { a2 = fminf(a1, b2); a1 = b1; ai = bi; }
      else a2 = fminf(a2, b1);
      const int sp = bx * 2 + nt;                // split: 128-col window, k-ordered
      const size_t o = (size_t)sp * Mm + (size_t)(m0 + tid);
      pd1[o] = a1; pd2[o] = a2; pi1[o] = ai;
    }
  }
}

// ---------------------------------------------------------------------------
// combine the NSPL partials per row; flag near-ties for np rescan
// ---------------------------------------------------------------------------
__global__ void k_combine(const float* __restrict__ pd1, const float* __restrict__ pd2,
                          const int* __restrict__ pi1, int* __restrict__ idxf,
                          int* __restrict__ rescan_cnt, int* __restrict__ rlist,
                          float* __restrict__ outIdx) {
  const int m = blockIdx.x * blockDim.x + threadIdx.x;
  if (m >= Mm) return;
  float a1 = INFINITY, a2 = INFINITY; int ai = 0x7fffffff;
  for (int spl = 0; spl < NSPL; ++spl) {         // spl ascending -> k ascending
    const size_t o = (size_t)spl * Mm + m;
    const float b1 = pd1[o], b2 = pd2[o]; const int bi = pi1[o];
    if (b1 < a1 || (b1 == a1 && bi < ai)) { a2 = fminf(a1, b2); a1 = b1; ai = bi; }
    else a2 = fminf(a2, b1);
  }
  idxf[m]   = ai;
  outIdx[m] = (float)ai;
  if (a2 - a1 <= RESCAN_MARGIN) { const int p = atomicAdd(rescan_cnt, 1); rlist[p] = m; }
}

// ---------------------------------------------------------------------------
// gather flagged rows into compact zg; np norms; init packed minima
// ---------------------------------------------------------------------------
__global__ void k_gather(const float* __restrict__ z, const int* __restrict__ rescan_cnt,
                         const int* __restrict__ rlist, float* __restrict__ zg,
                         float* __restrict__ Ag, unsigned long long* __restrict__ pbrow) {
  __shared__ float zr[Dd];
  const int cnt = min(*rescan_cnt, ZG_CAP);
  for (int it = blockIdx.x; it < cnt; it += gridDim.x) {
    const int m = rlist[it];
    const int b = m / Tt, t = m & (Tt - 1);
    __syncthreads();
    zr[threadIdx.x] = z[(size_t)b * Dd * Tt + (size_t)threadIdx.x * Tt + t];
    __syncthreads();
    zg[(size_t)it * Dd + threadIdx.x] = zr[threadIdx.x];
    if (threadIdx.x == 0) { Ag[it] = np_sumsq256(zr); pbrow[it] = ~0ull; }
  }
}

// ---------------------------------------------------------------------------
// chunked np-faithful rescan: packed (orderable f32, idx) atomicMin per row
// ---------------------------------------------------------------------------
__global__ __launch_bounds__(256)
void k_rescan_part(const float* __restrict__ cb, const float* __restrict__ sc,
                   const int* __restrict__ rescan_cnt, const float* __restrict__ zg,
                   const float* __restrict__ Ag, unsigned long long* __restrict__ pbrow) {
  __shared__ float  cs[CHK * 257];
  __shared__ float  scs[CHK];
  __shared__ float  zf[Dd];
  __shared__ double pr[256];
  const int tid = threadIdx.x;
  const int cnt = min(*rescan_cnt, ZG_CAP);
  const int c = blockIdx.x >> 4;
  const int g = blockIdx.x & (GRP - 1);
  if (g >= cnt) return;
  const int k0 = c * CHK;
  for (int i = tid; i < CHK * Dd; i += 256) {
    const int code = i >> 8, d = i & 255;
    cs[code * 257 + d] = cb[(size_t)(k0 + code) * Dd + d];
  }
  if (tid < CHK) scs[tid] = sc[k0 + tid];
  const int code = tid & 31, seg = tid >> 5;
  __syncthreads();
  for (int it = g; it < cnt; it += GRP) {
    zf[tid] = zg[(size_t)it * Dd + tid];
    __syncthreads();
    const float* cp = &cs[code * 257 + seg * 32];
    const float* zp = &zf[seg * 32];
    double a0 = 0.0, a1 = 0.0, a2 = 0.0, a3 = 0.0;
    #pragma unroll
    for (int j = 0; j < 32; j += 4) {
      a0 = fma((double)cp[j+0], (double)zp[j+0], a0);
      a1 = fma((double)cp[j+1], (double)zp[j+1], a1);
      a2 = fma((double)cp[j+2], (double)zp[j+2], a2);
      a3 = fma((double)cp[j+3], (double)zp[j+3], a3);
    }
    pr[tid] = (a0 + a1) + (a2 + a3);
    __syncthreads();
    if (tid < CHK) {
      double M8 = 0.0;
      #pragma unroll
      for (int sg = 0; sg < 8; ++sg) M8 += pr[tid + sg * 32];
      const float M  = (float)M8;
      const float t1 = __fsub_rn(Ag[it], __fmul_rn(2.0f, M));
      const float dq = __fadd_rn(t1, scs[tid]);
      unsigned int fb = __float_as_uint(dq);
      fb = (fb & 0x80000000u) ? ~fb : (fb | 0x80000000u);
      unsigned long long pack = ((unsigned long long)fb << 32) | (unsigned)(k0 + tid);
      #pragma unroll
      for (int off = 16; off; off >>= 1) {
        const unsigned long long o = __shfl_xor(pack, off);
        if (o < pack) pack = o;
      }
      if (tid == 0) atomicMin(pbrow + it, pack);
    }
    __syncthreads();
  }
}

__global__ void k_rescan_final(const int* __restrict__ rescan_cnt, const int* __restrict__ rlist,
                               const unsigned long long* __restrict__ pbrow,
                               int* __restrict__ idxf, float* __restrict__ outIdx) {
  const int cnt = min(*rescan_cnt, ZG_CAP);
  const int it = blockIdx.x * blockDim.x + threadIdx.x;
  if (it < cnt) {
    const int idx = (int)(unsigned)(pbrow[it] & 0xFFFFFFFFull);
    const int m = rlist[it];
    idxf[m] = idx; outIdx[m] = (float)idx;
  }
}

// overflow fallback: normally 0 iterations
__global__ void k_rescan_slow(const float* __restrict__ z, const float* __restrict__ cb,
                              const float* __restrict__ sc,
                              const int* __restrict__ rescan_cnt, const int* __restrict__ rlist,
                              int* __restrict__ idxf, float* __restrict__ outIdx) {
  __shared__ float zrow[Dd];
  __shared__ float Ash;
  __shared__ float sval[256];
  __shared__ int   sidx[256];
  const int tid = threadIdx.x;
  const int cnt = *rescan_cnt;
  for (int it = ZG_CAP + blockIdx.x; it < cnt; it += gridDim.x) {
    const int m = rlist[it];
    const int b = m / Tt, t = m & (Tt - 1);
    __syncthreads();
    zrow[tid] = z[(size_t)b * Dd * Tt + (size_t)tid * Tt + t];
    __syncthreads();
    if (tid == 0) Ash = np_sumsq256(zrow);
    __syncthreads();
    const float A = Ash;
    float best = INFINITY; int bi = 0x7fffffff;
    for (int k = tid; k < Kk; k += 256) {
      const float* cr = cb + (size_t)k * Dd;
      double a0 = 0.0, a1 = 0.0, a2 = 0.0, a3 = 0.0;
      for (int d = 0; d < Dd; d += 4) {
        const float4 c4 = *(const float4*)(cr + d);
        a0 = fma((double)c4.x, (double)zrow[d+0], a0);
        a1 = fma((double)c4.y, (double)zrow[d+1], a1);
        a2 = fma((double)c4.z, (double)zrow[d+2], a2);
        a3 = fma((double)c4.w, (double)zrow[d+3], a3);
      }
      const float M  = (float)((a0 + a1) + (a2 + a3));
      const float t1 = __fsub_rn(A, __fmul_rn(2.0f, M));
      const float dq = __fadd_rn(t1, sc[k]);
      if (dq < best) { best = dq; bi = k; }
    }
    sval[tid] = best; sidx[tid] = bi;
    __syncthreads();
    for (int off = 128; off; off >>= 1) {
      if (tid < off) {
        if (sval[tid+off] < sval[tid] ||
            (sval[tid+off] == sval[tid] && sidx[tid+off] < sidx[tid])) {
          sval[tid] = sval[tid+off]; sidx[tid] = sidx[tid+off];
        }
      }
      __syncthreads();
    }
    if (tid == 0) { idxf[m] = sidx[0]; outIdx[m] = (float)sidx[0]; }
    __syncthreads();
  }
}

// ---------------------------------------------------------------------------
// fused gather + transpose + STE + loss: out[b][d][t] = z + (cb[idx] - z)
// ---------------------------------------------------------------------------
__global__ void k_out(const float* __restrict__ z, const float* __restrict__ cb,
                      const int* __restrict__ idxf,
                      float* __restrict__ outZ, double* __restrict__ loss_accum) {
  __shared__ float tile[64][65];          // [d][t]
  const int tid = threadIdx.x;
  const int bidx = blockIdx.x;            // 8 * 4 * 32 = 1024
  const int b  = bidx >> 7;
  const int dt = (bidx >> 5) & 3;
  const int tt = bidx & 31;
  const int d0 = dt * 64, t0 = tt * 64;
  {
    const int r = tid >> 2, seg = tid & 3;
    const int idx = idxf[b * Tt + t0 + r];
    const float* src = cb + (size_t)idx * Dd + d0 + seg * 16;
    #pragma unroll
    for (int q4 = 0; q4 < 4; ++q4) {
      const float4 v = *(const float4*)(src + q4 * 4);
      tile[seg * 16 + q4 * 4 + 0][r] = v.x;
      tile[seg * 16 + q4 * 4 + 1][r] = v.y;
      tile[seg * 16 + q4 * 4 + 2][r] = v.z;
      tile[seg * 16 + q4 * 4 + 3][r] = v.w;
    }
  }
  __syncthreads();
  const float* zbase = z + ((size_t)b * Dd + d0) * Tt + t0;
  float*       obase = outZ + ((size_t)b * Dd + d0) * Tt + t0;
  double ls = 0.0;
  #pragma unroll
  for (int p = 0; p < 4; ++p) {
    const int d  = p * 16 + (tid >> 4);
    const int t4 = (tid & 15) * 4;
    const float4 zv = *(const float4*)(zbase + (size_t)d * Tt + t4);
    const float q0 = tile[d][t4+0], q1 = tile[d][t4+1];
    const float q2 = tile[d][t4+2], q3 = tile[d][t4+3];
    const float r0 = q0 - zv.x, r1 = q1 - zv.y, r2 = q2 - zv.z, r3 = q3 - zv.w;
    float4 o;
    o.x = zv.x + r0; o.y = zv.y + r1; o.z = zv.z + r2; o.w = zv.w + r3;
    *(float4*)(obase + (size_t)d * Tt + t4) = o;
    ls += (double)r0*r0 + (double)r1*r1 + (double)r2*r2 + (double)r3*r3;
  }
  #pragma unroll
  for (int off = 32; off; off >>= 1) ls += __shfl_down(ls, off);
  if ((tid & 63) == 0) atomicAdd(loss_accum, ls);
}

__global__ void k_finalize(const double* __restrict__ loss_accum, float* __restrict__ outLoss) {
  const double mean = *loss_accum / (double)((size_t)Bz * Dd * Tt);
  *outLoss = (float)(mean + 0.1 * mean);
}

// ---------------------------------------------------------------------------
extern "C" void kernel_launch(void* const* d_in, const int* in_sizes, int n_in,
                              void* d_out, int out_size, void* d_ws, size_t ws_size,
                              hipStream_t stream) {
  (void)in_sizes; (void)n_in; (void)out_size; (void)ws_size;
  const float* z  = (const float*)d_in[0];   // (B, D, T) fp32
  const float* cb = (const float*)d_in[1];   // (K, D)    fp32

  float* outZ    = (float*)d_out;
  float* outIdx  = outZ + (size_t)Bz * Dd * Tt;
  float* outLoss = outIdx + Mm;

  char* w = (char*)d_ws;
  double*    loss_accum = (double*)w;    w += 16;
  int*       rescan_cnt = (int*)w;       w += 16;
  int*       rlist      = (int*)w;       w += sizeof(int)   * Mm;
  int*       idxf       = (int*)w;       w += sizeof(int)   * Mm;
  float*     sc         = (float*)w;     w += sizeof(float) * Kk;
  _Float16*  Ah         = (_Float16*)w;  w += sizeof(_Float16) * (size_t)Mm * Dd;
  _Float16*  Bh         = (_Float16*)w;  w += sizeof(_Float16) * (size_t)Kk * Dd;
  float*     zg         = (float*)w;     w += sizeof(float) * (size_t)ZG_CAP * Dd;
  float*     Ag         = (float*)w;     w += sizeof(float) * ZG_CAP;
  unsigned long long* pbrow = (unsigned long long*)w; w += sizeof(unsigned long long) * ZG_CAP;
  float*     pd1        = (float*)w;     w += sizeof(float) * (size_t)NSPL * Mm;
  float*     pd2        = (float*)w;     w += sizeof(float) * (size_t)NSPL * Mm;
  int*       pi1        = (int*)w;       /* total ~30 MB */

  k_pre         <<<dim3(2304), 256, 0, stream>>>(z, cb, Ah, Bh, sc, loss_accum, rescan_cnt);
  k_mfma        <<<dim3((Mm / 128) * (Kk / 256)), 256, 0, stream>>>(Ah, Bh, sc, pd1, pd2, pi1);
  k_combine     <<<dim3(Mm / 256), 256, 0, stream>>>(pd1, pd2, pi1, idxf, rescan_cnt, rlist, outIdx);
  k_gather      <<<dim3(256), 256, 0, stream>>>(z, rescan_cnt, rlist, zg, Ag, pbrow);
  k_rescan_part <<<dim3((Kk / CHK) * GRP), 256, 0, stream>>>(cb, sc, rescan_cnt, zg, Ag, pbrow);
  k_rescan_slow <<<dim3(64), 256, 0, stream>>>(z, cb, sc, rescan_cnt, rlist, idxf, outIdx);
  k_rescan_final<<<dim3(ZG_CAP / 256), 256, 0, stream>>>(rescan_cnt, rlist, pbrow, idxf, outIdx);
  k_out         <<<dim3(1024), 256, 0, stream>>>(z, cb, idxf, outZ, loss_accum);
  k_finalize    <<<dim3(1), 1, 0, stream>>>(loss_accum, outLoss);
}